// Round 1
// baseline (84.556 us; speedup 1.0000x reference)
//
#include <hip/hip_runtime.h>

// B=8, N=128, C=3, F=64, K=64
#define Bz 8
#define Nz 128
#define Cz 3
#define Fz 64
#define Kz 64

// Kernel A: P[which][bn][c][k] = sum_f vf[bn][c][f] * w_vs[which*F + f][k]
// P laid out flat in ws: idx = which*(B*N*C*K) + bn*(C*K) + c*K + k
__global__ void proj_kernel(const float* __restrict__ vf,
                            const float* __restrict__ w,
                            float* __restrict__ P) {
    int idx = blockIdx.x * blockDim.x + threadIdx.x;   // [0, 2*B*N*C*K) exact
    const int PER = Bz * Nz * Cz * Kz;                 // 196608
    int which = idx / PER;
    int rem   = idx - which * PER;
    int k  = rem & (Kz - 1);
    int c  = (rem >> 6) % Cz;
    int bn = rem / (Cz * Kz);

    const float* vrow = vf + (bn * Cz + c) * Fz;       // 64 contiguous floats
    const float* wcol = w + which * Fz * Kz + k;       // stride-K column
    float acc = 0.f;
    #pragma unroll 8
    for (int f = 0; f < Fz; ++f)
        acc += vrow[f] * wcol[f * Kz];
    P[idx] = acc;
}

// Kernel B: out[b,i,j,k] = relu( sum_c d[b,i,j,c]*(Pi[b,i,c,k]+Pj[b,j,c,k])
//                                + (sum_c d[b,i,j,c]) * b_vs[k] )
// One float4 (4 consecutive k) per thread.
__global__ void pair_kernel(const float* __restrict__ d,
                            const float4* __restrict__ P4,
                            const float4* __restrict__ bvs4,
                            float4* __restrict__ out4) {
    int tid = blockIdx.x * blockDim.x + threadIdx.x;   // [0, B*N*N*K/4) exact
    int k4 = tid & 15;                                 // K/4 = 16
    int j  = (tid >> 4) & (Nz - 1);
    int i  = (tid >> 11) & (Nz - 1);
    int b  = tid >> 18;

    const float* dp = d + (((b * Nz + i) * Nz) + j) * Cz;
    float d0 = dp[0], d1 = dp[1], d2 = dp[2];
    float dsum = d0 + d1 + d2;

    const int PER4 = (Bz * Nz * Cz * Kz) / 4;          // 49152
    const float4* pi = P4 + (b * Nz + i) * (Cz * Kz / 4) + k4;
    const float4* pj = P4 + PER4 + (b * Nz + j) * (Cz * Kz / 4) + k4;

    float4 a0 = pi[0],  a1 = pi[16], a2 = pi[32];
    float4 c0 = pj[0],  c1 = pj[16], c2 = pj[32];
    float4 bv = bvs4[k4];

    float4 r;
    r.x = fmaxf(d0 * (a0.x + c0.x) + d1 * (a1.x + c1.x) + d2 * (a2.x + c2.x) + dsum * bv.x, 0.f);
    r.y = fmaxf(d0 * (a0.y + c0.y) + d1 * (a1.y + c1.y) + d2 * (a2.y + c2.y) + dsum * bv.y, 0.f);
    r.z = fmaxf(d0 * (a0.z + c0.z) + d1 * (a1.z + c1.z) + d2 * (a2.z + c2.z) + dsum * bv.z, 0.f);
    r.w = fmaxf(d0 * (a0.w + c0.w) + d1 * (a1.w + c1.w) + d2 * (a2.w + c2.w) + dsum * bv.w, 0.f);
    out4[tid] = r;
}

extern "C" void kernel_launch(void* const* d_in, const int* in_sizes, int n_in,
                              void* d_out, int out_size, void* d_ws, size_t ws_size,
                              hipStream_t stream) {
    const float* vf  = (const float*)d_in[0];   // (B,N,C,F)
    const float* dst = (const float*)d_in[1];   // (B,N,N,C)
    const float* w   = (const float*)d_in[2];   // (2F,K)
    const float* bvs = (const float*)d_in[3];   // (K,)
    float* out = (float*)d_out;
    float* P   = (float*)d_ws;                  // 2*B*N*C*K floats = 1.57 MB

    // Kernel A: 2*B*N*C*K = 393216 threads
    {
        int total = 2 * Bz * Nz * Cz * Kz;
        int block = 256;
        int grid = total / block;               // exact: 1536
        proj_kernel<<<grid, block, 0, stream>>>(vf, w, P);
    }
    // Kernel B: B*N*N*K/4 = 2097152 threads
    {
        int total = Bz * Nz * Nz * Kz / 4;
        int block = 256;
        int grid = total / block;               // exact: 8192
        pair_kernel<<<grid, block, 0, stream>>>(dst, (const float4*)P,
                                                (const float4*)bvs, (float4*)out);
    }
}

// Round 2
// 79.811 us; speedup vs baseline: 1.0594x; 1.0594x over previous
//
#include <hip/hip_runtime.h>

// B=8, N=128, C=3, F=64, K=64
#define Bz 8
#define Nz 128
#define Cz 3
#define Fz 64
#define Kz 64

// Kernel A: P'[which][bn][c][k] = sum_f vf[bn][c][f] * w_vs[which*F + f][k]
//                                 + (which==0 ? b_vs[k] : 0)
// float4-vectorized over k: one float4 (4 k) per thread.
// P laid out flat in ws (float4 units): idx4 = which*49152 + bn*48 + c*16 + k4
__global__ __launch_bounds__(256) void proj_kernel(const float* __restrict__ vf,
                                                   const float4* __restrict__ w4,
                                                   const float4* __restrict__ bv4,
                                                   float4* __restrict__ P4) {
    int idx = blockIdx.x * blockDim.x + threadIdx.x;   // [0, 2*B*N*C*K/4) = [0, 98304)
    const int PER4 = (Bz * Nz * Cz * Kz) / 4;          // 49152
    int which = idx / PER4;
    int rem   = idx - which * PER4;
    int k4 = rem & 15;
    int c  = (rem >> 4) % Cz;
    int bn = rem / (Cz * Kz / 4);                      // rem / 48

    const float*  vrow = vf + (bn * Cz + c) * Fz;      // 64 contiguous floats (wave-uniform per 16 lanes)
    const float4* wcol = w4 + which * (Fz * Kz / 4) + k4;  // stride-16 float4 column

    float4 acc = make_float4(0.f, 0.f, 0.f, 0.f);
    #pragma unroll 8
    for (int f = 0; f < Fz; ++f) {
        float v = vrow[f];
        float4 wv = wcol[f * 16];
        acc.x += v * wv.x; acc.y += v * wv.y; acc.z += v * wv.z; acc.w += v * wv.w;
    }
    if (which == 0) {
        float4 bv = bv4[k4];
        acc.x += bv.x; acc.y += bv.y; acc.z += bv.z; acc.w += bv.w;
    }
    P4[idx] = acc;
}

// Kernel B: out[b,i,j,k] = relu( sum_c d[b,i,j,c] * (Pi'[b,i,c,k] + Pj[b,j,c,k]) )
// Thread fixes (b, i, k4), preloads Pi' (3 float4) in registers, loops 8 j.
__global__ __launch_bounds__(256) void pair_kernel(const float* __restrict__ d,
                                                   const float4* __restrict__ P4,
                                                   float4* __restrict__ out4) {
    const int PER4 = (Bz * Nz * Cz * Kz) / 4;          // 49152
    int t   = threadIdx.x;
    int k4  = t & 15;
    int jc  = (t >> 4) & 15;                           // j chunk: j = jc*8 + jj
    int i   = blockIdx.x & (Nz - 1);
    int b   = blockIdx.x >> 7;

    const float4* pi = P4 + (b * Nz + i) * 48 + k4;
    float4 a0 = pi[0], a1 = pi[16], a2 = pi[32];       // Pi' (bias folded in)

    const float*  drow = d + ((b * Nz + i) * Nz) * Cz;
    const float4* pjb  = P4 + PER4 + (b * Nz) * 48 + k4;
    float4*       ob   = out4 + ((b * Nz + i) * Nz) * 16 + k4;

    #pragma unroll
    for (int jj = 0; jj < 8; ++jj) {
        int j = jc * 8 + jj;
        const float* dp = drow + j * 3;
        float d0 = dp[0], d1 = dp[1], d2 = dp[2];

        const float4* pj = pjb + j * 48;
        float4 c0 = pj[0], c1 = pj[16], c2 = pj[32];

        float4 r;
        r.x = fmaxf(d0 * (a0.x + c0.x) + d1 * (a1.x + c1.x) + d2 * (a2.x + c2.x), 0.f);
        r.y = fmaxf(d0 * (a0.y + c0.y) + d1 * (a1.y + c1.y) + d2 * (a2.y + c2.y), 0.f);
        r.z = fmaxf(d0 * (a0.z + c0.z) + d1 * (a1.z + c1.z) + d2 * (a2.z + c2.z), 0.f);
        r.w = fmaxf(d0 * (a0.w + c0.w) + d1 * (a1.w + c1.w) + d2 * (a2.w + c2.w), 0.f);
        ob[j * 16] = r;
    }
}

extern "C" void kernel_launch(void* const* d_in, const int* in_sizes, int n_in,
                              void* d_out, int out_size, void* d_ws, size_t ws_size,
                              hipStream_t stream) {
    const float* vf  = (const float*)d_in[0];   // (B,N,C,F)
    const float* dst = (const float*)d_in[1];   // (B,N,N,C)
    const float* w   = (const float*)d_in[2];   // (2F,K)
    const float* bvs = (const float*)d_in[3];   // (K,)
    float* out = (float*)d_out;
    float* P   = (float*)d_ws;                  // 2*B*N*C*K floats = 1.57 MB

    // Kernel A: 2*B*N*C*K/4 = 98304 threads -> 384 blocks
    proj_kernel<<<384, 256, 0, stream>>>(vf, (const float4*)w,
                                         (const float4*)bvs, (float4*)P);
    // Kernel B: B*N blocks (1024), each thread does 8 j-values
    pair_kernel<<<Bz * Nz, 256, 0, stream>>>(dst, (const float4*)P, (float4*)out);
}